// Round 4
// baseline (292.810 us; speedup 1.0000x reference)
//
#include <hip/hip_runtime.h>
#include <hip/hip_bf16.h>
#include <stdint.h>

// Bahdanau attention. B=32, T=2048, D=512, U=512.
// d_out: context[B,D] (16384 f32) then attention_weights[B,T,1] (65536 f32)

#define B_DIM 32
#define T_DIM 2048
#define D_DIM 512
#define U_DIM 512
#define M_DIM (B_DIM * T_DIM)   // 65536 rows

typedef short bf16x8 __attribute__((ext_vector_type(8)));
typedef float f32x4 __attribute__((ext_vector_type(4)));

__device__ __forceinline__ float fast_tanh(float x) {
    float e = __expf(2.0f * x);
    return 1.0f - __fdividef(2.0f, e + 1.0f);
}

// scalar RNE f32->bf16 (prep only)
__device__ __forceinline__ short bf16r(float x) {
    unsigned u = __float_as_uint(x);
    u += 0x7fffu + ((u >> 16) & 1u);
    return (short)(u >> 16);
}

// packed RNE conversion (v_cvt_pk_bf16_f32 path) for the score hot loop
__device__ __forceinline__ bf16x8 pack8(float4 a, float4 b) {
    union { __hip_bfloat162 h[4]; bf16x8 v; } u;
    u.h[0] = __float22bfloat162_rn(make_float2(a.x, a.y));
    u.h[1] = __float22bfloat162_rn(make_float2(a.z, a.w));
    u.h[2] = __float22bfloat162_rn(make_float2(b.x, b.y));
    u.h[3] = __float22bfloat162_rn(make_float2(b.z, b.w));
    return u.v;
}

// async global->LDS, 16B per lane (dest = wave-uniform base + lane*16;
// call sites keep lane-linear LDS addresses). R3-proven correct.
__device__ __forceinline__ void g2lds16(const void* g, void* lds) {
    auto gp = reinterpret_cast<const __attribute__((address_space(1))) unsigned int*>(
        reinterpret_cast<uintptr_t>(g));
    auto lp = reinterpret_cast<__attribute__((address_space(3))) unsigned int*>(
        (unsigned int)(uintptr_t)lds);
    __builtin_amdgcn_global_load_lds(gp, lp, 16, 0, 0);
}

// ---------------------------------------------------------------------------
// W1T layout in 16-byte units (8 bf16 along k):
//   unit n = ut*16384 + kstep*1024 + kc*256 + uu
//   where u = ut*256+uu, k = kstep*32 + kc*8 + j.
// Chunk (ut,kstep) = 1024 units = 16 KiB, contiguous -> pure linear
// global_load_lds staging; frag reads are 256B-contiguous per quad (kc).
// ---------------------------------------------------------------------------

// Kernel 1: prep.
//   blocks [0,128): W1T (1 unit/thread; reads coalesced in u, writes linear)
//   blocks [128,384): qb[b][u] = query[b]@W2_w[:,u] + W2_b[u] + W1_b[u]
//   V_b dropped (softmax shift-invariance).
__global__ void prep_kernel(const float* __restrict__ W1_w,
                            const float* __restrict__ W1_b,
                            const float* __restrict__ W2_w,
                            const float* __restrict__ W2_b,
                            const float* __restrict__ query,
                            unsigned short* __restrict__ W1T,
                            float* __restrict__ qb) {
    __shared__ float red[256];
    const int tid = threadIdx.x;
    if (blockIdx.x < 128) {
        int n = blockIdx.x * 256 + tid;   // unit id 0..32767
        int uu    = n & 255;
        int kc    = (n >> 8) & 3;
        int kstep = (n >> 10) & 15;
        int ut    = n >> 14;
        int u  = ut * 256 + uu;
        int k0 = kstep * 32 + kc * 8;
        bf16x8 pk;
#pragma unroll
        for (int j = 0; j < 8; ++j)
            pk[j] = bf16r(W1_w[(size_t)(k0 + j) * U_DIM + u]);  // coalesced in u
        ((bf16x8*)W1T)[n] = pk;
    } else {
        int bid = blockIdx.x - 128;       // 0..255
        int b  = bid >> 3;
        int ug = bid & 7;
        int u  = ug * 64 + (tid & 63);
        int dq = tid >> 6;                // 0..3 (128 d each)
        const float* q  = query + b * D_DIM + dq * 128;
        const float* w2 = W2_w + (size_t)(dq * 128) * U_DIM + u;
        float acc = 0.f;
#pragma unroll 8
        for (int d = 0; d < 128; ++d)
            acc += q[d] * w2[(size_t)d * U_DIM];
        red[tid] = acc;
        __syncthreads();
        if (tid < 64) {
            qb[b * U_DIM + u] = red[tid] + red[tid + 64] + red[tid + 128]
                              + red[tid + 192] + W2_b[u] + W1_b[u];
        }
    }
}

// ---------------------------------------------------------------------------
// Kernel 2: fused score GEMM. 2048 blocks x 256 thr.
// Block: 64 m-rows x 256 u (ut = bid&1 picks u-half). 4 waves: wr=w>>1 (32 m),
// wc=w&1 (128 u). Wave: 2 m-tiles x 8 u-tiles of 16x16 -> 16 f32x4 acc.
// Per BK=32 step: A-frags straight from global (16 rows x 128B window fully
// consumed per instruction pair -> coalesced), B via global_load_lds.
// Epilogue once after full K: tanh+Vw, reduce over u, partials to sP slice.
// ---------------------------------------------------------------------------
__global__ __launch_bounds__(256, 2) void score_kernel(
        const float* __restrict__ values,
        const unsigned short* __restrict__ W1T,
        const float* __restrict__ qb,
        const float* __restrict__ Vw,
        float* __restrict__ sP) {
    __shared__ __align__(16) unsigned char smem[16384];

    const int tid  = threadIdx.x;
    const int lane = tid & 63;
    const int w    = tid >> 6;
    const int l15  = lane & 15;
    const int quad = lane >> 4;
    const int wr   = w >> 1, wc = w & 1;
    const int ut    = blockIdx.x & 1;
    const int mtile = blockIdx.x >> 1;
    const int mb    = mtile * 64;
    const int b     = mb >> 11;          // 64 | 2048

    const float* arow0 = values + (size_t)(mb + wr * 32 + l15) * D_DIM + quad * 8;
    const float* arow1 = arow0 + 16 * D_DIM;

    f32x4 acc[2][8] = {};

    for (int ks = 0; ks < 16; ++ks) {
        // A for this step (global -> regs; overlaps with B staging drain)
        float4 a00 = *(const float4*)(arow0 + ks * 32);
        float4 a01 = *(const float4*)(arow0 + ks * 32 + 4);
        float4 a10 = *(const float4*)(arow1 + ks * 32);
        float4 a11 = *(const float4*)(arow1 + ks * 32 + 4);

        __syncthreads();   // previous step's B reads done
        const unsigned short* src = W1T + (size_t)(ut * 16 + ks) * 8192;
#pragma unroll
        for (int i = 0; i < 4; ++i) {
            int unit = i * 256 + w * 64 + lane;   // lane-linear
            g2lds16(src + (size_t)unit * 8, smem + unit * 16);
        }
        __syncthreads();   // B ready (barrier drains vmcnt incl. A loads)

        bf16x8 a0 = pack8(a00, a01);
        bf16x8 a1 = pack8(a10, a11);
        const unsigned char* bbase = smem + (size_t)(quad * 256 + wc * 128 + l15) * 16;
#pragma unroll
        for (int ui = 0; ui < 8; ++ui) {
            bf16x8 bf = *(const bf16x8*)(bbase + ui * 256);   // 256B-contig/quad
            acc[0][ui] = __builtin_amdgcn_mfma_f32_16x16x32_bf16(a0, bf, acc[0][ui], 0, 0, 0);
            acc[1][ui] = __builtin_amdgcn_mfma_f32_16x16x32_bf16(a1, bf, acc[1][ui], 0, 0, 0);
        }
    }

    // ---- epilogue (once): tanh + Vw, reduce over u ----
    const int ub = ut * 256 + wc * 128 + l15;
    float sm[2][4] = {};
#pragma unroll
    for (int ui = 0; ui < 8; ++ui) {
        const int u = ub + ui * 16;
        const float qv = qb[b * U_DIM + u];
        const float vw = Vw[u];
#pragma unroll
        for (int mt = 0; mt < 2; ++mt)
#pragma unroll
            for (int r = 0; r < 4; ++r)
                sm[mt][r] += fast_tanh(acc[mt][ui][r] + qv) * vw;
    }
#pragma unroll
    for (int mt = 0; mt < 2; ++mt)
#pragma unroll
        for (int r = 0; r < 4; ++r) {
            float v = sm[mt][r];
            v += __shfl_xor(v, 1, 64);
            v += __shfl_xor(v, 2, 64);
            v += __shfl_xor(v, 4, 64);
            v += __shfl_xor(v, 8, 64);
            sm[mt][r] = v;
        }
    if (l15 == 0) {
        const int slice = ut * 2 + wc;
#pragma unroll
        for (int mt = 0; mt < 2; ++mt)
#pragma unroll
            for (int r = 0; r < 4; ++r)
                sP[slice * M_DIM + mb + wr * 32 + mt * 16 + quad * 4 + r] = sm[mt][r];
    }
}

// ---------------------------------------------------------------------------
// Kernel 3: softmax over T per batch; sums the 4 score slices; writes weights.
// ---------------------------------------------------------------------------
__global__ void softmax_kernel(const float* __restrict__ sP,
                               float* __restrict__ out) {
    const int b = blockIdx.x;
    const int tid = threadIdx.x;

    float v[8];
    float mx = -1e30f;
#pragma unroll
    for (int i = 0; i < 8; ++i) {
        int m = b * T_DIM + i * 256 + tid;
        v[i] = sP[m] + sP[M_DIM + m] + sP[2 * M_DIM + m] + sP[3 * M_DIM + m];
        mx = fmaxf(mx, v[i]);
    }
#pragma unroll
    for (int off = 1; off < 64; off <<= 1)
        mx = fmaxf(mx, __shfl_xor(mx, off, 64));
    __shared__ float redm[4];
    if ((tid & 63) == 0) redm[tid >> 6] = mx;
    __syncthreads();
    mx = fmaxf(fmaxf(redm[0], redm[1]), fmaxf(redm[2], redm[3]));

    float sum = 0.f;
#pragma unroll
    for (int i = 0; i < 8; ++i) {
        v[i] = __expf(v[i] - mx);
        sum += v[i];
    }
#pragma unroll
    for (int off = 1; off < 64; off <<= 1)
        sum += __shfl_xor(sum, off, 64);
    __shared__ float reds[4];
    if ((tid & 63) == 0) reds[tid >> 6] = sum;
    __syncthreads();
    sum = reds[0] + reds[1] + reds[2] + reds[3];

    const float inv = 1.0f / sum;
#pragma unroll
    for (int i = 0; i < 8; ++i)
        out[B_DIM * D_DIM + b * T_DIM + i * 256 + tid] = v[i] * inv;
}

// ---------------------------------------------------------------------------
// Kernel 4: context partials. grid (32 tc, 32 b) x 256 thr. Block covers 64 t
// x all 512 d; two t-interleaved halves combined in LDS; partial -> P (no
// atomics). values L3-warm from score.
// ---------------------------------------------------------------------------
__global__ void context_kernel(const float* __restrict__ values,
                               const float* __restrict__ weights,
                               float* __restrict__ P) {
    __shared__ float sw[64];
    __shared__ float red[512];
    const int tc = blockIdx.x;   // 0..31 (64 t each)
    const int b  = blockIdx.y;
    const int tid = threadIdx.x;
    const int d4 = tid & 127;    // float4 column
    const int th = tid >> 7;     // t-interleave half

    if (tid < 64) sw[tid] = weights[b * T_DIM + tc * 64 + tid];
    __syncthreads();

    const float4* vb = (const float4*)(values + ((size_t)b * T_DIM + tc * 64) * D_DIM) + d4;
    float4 acc = {0.f, 0.f, 0.f, 0.f};
#pragma unroll 8
    for (int i = th; i < 64; i += 2) {
        float wv = sw[i];
        float4 vv = vb[(size_t)i * 128];
        acc.x += wv * vv.x; acc.y += wv * vv.y;
        acc.z += wv * vv.z; acc.w += wv * vv.w;
    }
    if (th == 1) ((float4*)red)[d4] = acc;
    __syncthreads();
    if (th == 0) {
        float4 o = ((float4*)red)[d4];
        acc.x += o.x; acc.y += o.y; acc.z += o.z; acc.w += o.w;
        *(float4*)(P + ((size_t)(b * 32 + tc)) * 512 + d4 * 4) = acc;
    }
}

// Kernel 5: reduce the 32 t-chunk partials -> context output.
__global__ void reduce_kernel(const float* __restrict__ P,
                              float* __restrict__ ctx) {
    const int g = blockIdx.x * 256 + threadIdx.x;   // 0..16383
    const int b = g >> 9, d = g & 511;
    float s = 0.f;
#pragma unroll
    for (int tc = 0; tc < 32; ++tc)
        s += P[((size_t)(b * 32 + tc)) * 512 + d];
    ctx[g] = s;
}

// ---------------------------------------------------------------------------
extern "C" void kernel_launch(void* const* d_in, const int* in_sizes, int n_in,
                              void* d_out, int out_size, void* d_ws, size_t ws_size,
                              hipStream_t stream) {
    const float* values = (const float*)d_in[0];
    const float* query  = (const float*)d_in[1];
    const float* W1_w   = (const float*)d_in[2];
    const float* W1_b   = (const float*)d_in[3];
    const float* W2_w   = (const float*)d_in[4];
    const float* W2_b   = (const float*)d_in[5];
    const float* V_w    = (const float*)d_in[6];
    // V_b (d_in[7]) dropped: softmax is shift-invariant.

    float* out = (float*)d_out;

    unsigned char* ws = (unsigned char*)d_ws;
    unsigned short* W1T = (unsigned short*)(ws);             // 512 KiB
    float* qb = (float*)(ws + 524288);                       // 64 KiB
    float* sP = (float*)(ws + 524288 + 65536);               // 1 MiB (4 slices)
    float* P  = (float*)(ws + 524288 + 65536 + 1048576);     // 2 MiB

    prep_kernel<<<384, 256, 0, stream>>>(W1_w, W1_b, W2_w, W2_b, query, W1T, qb);
    score_kernel<<<2048, 256, 0, stream>>>(values, W1T, qb, V_w, sP);
    softmax_kernel<<<B_DIM, 256, 0, stream>>>(sP, out);
    context_kernel<<<dim3(32, B_DIM), 256, 0, stream>>>(values, out + B_DIM * D_DIM, P);
    reduce_kernel<<<64, 256, 0, stream>>>(P, out);
}

// Round 5
// 282.376 us; speedup vs baseline: 1.0370x; 1.0370x over previous
//
#include <hip/hip_runtime.h>
#include <hip/hip_bf16.h>
#include <stdint.h>

// Bahdanau attention. B=32, T=2048, D=512, U=512.
// d_out: context[B,D] (16384 f32) then attention_weights[B,T,1] (65536 f32)

#define B_DIM 32
#define T_DIM 2048
#define D_DIM 512
#define U_DIM 512
#define M_DIM (B_DIM * T_DIM)   // 65536 rows

typedef short bf16x8 __attribute__((ext_vector_type(8)));
typedef float f32x4 __attribute__((ext_vector_type(4)));

__device__ __forceinline__ float fast_tanh(float x) {
    float e = __expf(2.0f * x);
    return 1.0f - __fdividef(2.0f, e + 1.0f);
}

// scalar RNE f32->bf16 (prep only)
__device__ __forceinline__ short bf16r(float x) {
    unsigned u = __float_as_uint(x);
    u += 0x7fffu + ((u >> 16) & 1u);
    return (short)(u >> 16);
}

// packed RNE conversion for the score hot loop
__device__ __forceinline__ bf16x8 pack8(float4 a, float4 b) {
    union { __hip_bfloat162 h[4]; bf16x8 v; } u;
    u.h[0] = __float22bfloat162_rn(make_float2(a.x, a.y));
    u.h[1] = __float22bfloat162_rn(make_float2(a.z, a.w));
    u.h[2] = __float22bfloat162_rn(make_float2(b.x, b.y));
    u.h[3] = __float22bfloat162_rn(make_float2(b.z, b.w));
    return u.v;
}

// async global->LDS, 16B per lane (dest = wave-uniform base + lane*16;
// call sites keep lane-linear LDS addresses). R3/R4-proven correct.
__device__ __forceinline__ void g2lds16(const void* g, void* lds) {
    auto gp = reinterpret_cast<const __attribute__((address_space(1))) unsigned int*>(
        reinterpret_cast<uintptr_t>(g));
    auto lp = reinterpret_cast<__attribute__((address_space(3))) unsigned int*>(
        (unsigned int)(uintptr_t)lds);
    __builtin_amdgcn_global_load_lds(gp, lp, 16, 0, 0);
}

// ---------------------------------------------------------------------------
// W1T layout in 16-byte units (8 bf16 along k):
//   unit n = ut*16384 + kstep*1024 + kc*256 + uu
//   where u = ut*256+uu, k = kstep*32 + kc*8 + j.
// Chunk (ut,kstep) = 1024 units = 16 KiB, contiguous -> pure linear
// global_load_lds staging; frag reads are 256B-contiguous per quad (kc).
// ---------------------------------------------------------------------------

// Kernel 1: prep. (unchanged from R4)
__global__ void prep_kernel(const float* __restrict__ W1_w,
                            const float* __restrict__ W1_b,
                            const float* __restrict__ W2_w,
                            const float* __restrict__ W2_b,
                            const float* __restrict__ query,
                            unsigned short* __restrict__ W1T,
                            float* __restrict__ qb) {
    __shared__ float red[256];
    const int tid = threadIdx.x;
    if (blockIdx.x < 128) {
        int n = blockIdx.x * 256 + tid;   // unit id 0..32767
        int uu    = n & 255;
        int kc    = (n >> 8) & 3;
        int kstep = (n >> 10) & 15;
        int ut    = n >> 14;
        int u  = ut * 256 + uu;
        int k0 = kstep * 32 + kc * 8;
        bf16x8 pk;
#pragma unroll
        for (int j = 0; j < 8; ++j)
            pk[j] = bf16r(W1_w[(size_t)(k0 + j) * U_DIM + u]);  // coalesced in u
        ((bf16x8*)W1T)[n] = pk;
    } else {
        int bid = blockIdx.x - 128;       // 0..255
        int b  = bid >> 3;
        int ug = bid & 7;
        int u  = ug * 64 + (tid & 63);
        int dq = tid >> 6;                // 0..3 (128 d each)
        const float* q  = query + b * D_DIM + dq * 128;
        const float* w2 = W2_w + (size_t)(dq * 128) * U_DIM + u;
        float acc = 0.f;
#pragma unroll 8
        for (int d = 0; d < 128; ++d)
            acc += q[d] * w2[(size_t)d * U_DIM];
        red[tid] = acc;
        __syncthreads();
        if (tid < 64) {
            qb[b * U_DIM + u] = red[tid] + red[tid + 64] + red[tid + 128]
                              + red[tid + 192] + W2_b[u] + W1_b[u];
        }
    }
}

// ---------------------------------------------------------------------------
// Kernel 2: fused score GEMM. 1024 blocks x 512 thr (8 waves).
// Block: 128 m x 256 u (ut = bid&1). Waves: wr=w>>1 (32 m), wc=w&1 (128 u).
// Wave: 2 m-tiles x 8 u-tiles -> 16 f32x4 acc (64 VGPR, below spill zone).
// DOUBLE-BUFFERED B: stage slab ks+1 (16 KiB, global_load_lds) is issued
// right AFTER the per-step barrier, so it flies through the whole MFMA phase
// and only drains at the NEXT barrier. A(ks) prefetched before the barrier.
// One barrier per K-step.
// ---------------------------------------------------------------------------
__global__ __launch_bounds__(512, 4) void score_kernel(
        const float* __restrict__ values,
        const unsigned short* __restrict__ W1T,
        const float* __restrict__ qb,
        const float* __restrict__ Vw,
        float* __restrict__ sP) {
    __shared__ __align__(16) unsigned char smem[2][16384];

    const int tid  = threadIdx.x;
    const int lane = tid & 63;
    const int w    = tid >> 6;       // 0..7
    const int l15  = lane & 15;
    const int quad = lane >> 4;
    const int wr   = w >> 1;         // 0..3 : 32 m-rows each
    const int wc   = w & 1;          // 0..1 : 128 u each
    const int ut    = blockIdx.x & 1;
    const int mb    = (blockIdx.x >> 1) * 128;
    const int b     = mb >> 11;      // 128 | 2048

    const float* arow0 = values + (size_t)(mb + wr * 32 + l15) * D_DIM + quad * 8;
    const float* arow1 = arow0 + 16 * D_DIM;
    const unsigned short* wsrc = W1T + (size_t)ut * 16 * 8192;

    // stage slab 0 -> buf0 (2 units of 16B per thread, lane-linear)
#pragma unroll
    for (int i = 0; i < 2; ++i) {
        int unit = i * 512 + w * 64 + lane;
        g2lds16(wsrc + (size_t)unit * 8, smem[0] + unit * 16);
    }

    f32x4 acc[2][8] = {};

    for (int ks = 0; ks < 16; ++ks) {
        // A for this step — in flight across the barrier drain
        float4 a00 = *(const float4*)(arow0 + ks * 32);
        float4 a01 = *(const float4*)(arow0 + ks * 32 + 4);
        float4 a10 = *(const float4*)(arow1 + ks * 32);
        float4 a11 = *(const float4*)(arow1 + ks * 32 + 4);

        __syncthreads();   // slab ks staged; everyone done reading other buf

        // issue staging of slab ks+1 into the other buffer; overlaps MFMAs
        if (ks < 15) {
            const unsigned short* src = wsrc + (size_t)(ks + 1) * 8192;
            unsigned char* nbuf = smem[(ks + 1) & 1];
#pragma unroll
            for (int i = 0; i < 2; ++i) {
                int unit = i * 512 + w * 64 + lane;
                g2lds16(src + (size_t)unit * 8, nbuf + unit * 16);
            }
        }

        bf16x8 a0 = pack8(a00, a01);
        bf16x8 a1 = pack8(a10, a11);
        const unsigned char* bbase =
            smem[ks & 1] + (size_t)(quad * 256 + wc * 128 + l15) * 16;
#pragma unroll
        for (int ui = 0; ui < 8; ++ui) {
            bf16x8 bf = *(const bf16x8*)(bbase + ui * 256);   // 256B-contig/quad
            acc[0][ui] = __builtin_amdgcn_mfma_f32_16x16x32_bf16(a0, bf, acc[0][ui], 0, 0, 0);
            acc[1][ui] = __builtin_amdgcn_mfma_f32_16x16x32_bf16(a1, bf, acc[1][ui], 0, 0, 0);
        }
    }

    // ---- epilogue (once): tanh + Vw, reduce over u ----
    const int ub = ut * 256 + wc * 128 + l15;
    float sm[2][4] = {};
#pragma unroll
    for (int ui = 0; ui < 8; ++ui) {
        const int u = ub + ui * 16;
        const float qv = qb[b * U_DIM + u];
        const float vw = Vw[u];
#pragma unroll
        for (int mt = 0; mt < 2; ++mt)
#pragma unroll
            for (int r = 0; r < 4; ++r)
                sm[mt][r] += fast_tanh(acc[mt][ui][r] + qv) * vw;
    }
#pragma unroll
    for (int mt = 0; mt < 2; ++mt)
#pragma unroll
        for (int r = 0; r < 4; ++r) {
            float v = sm[mt][r];
            v += __shfl_xor(v, 1, 64);
            v += __shfl_xor(v, 2, 64);
            v += __shfl_xor(v, 4, 64);
            v += __shfl_xor(v, 8, 64);
            sm[mt][r] = v;
        }
    if (l15 == 0) {
        const int slice = ut * 2 + wc;
#pragma unroll
        for (int mt = 0; mt < 2; ++mt)
#pragma unroll
            for (int r = 0; r < 4; ++r)
                sP[slice * M_DIM + mb + wr * 32 + mt * 16 + quad * 4 + r] = sm[mt][r];
    }
}

// ---------------------------------------------------------------------------
// Kernel 3: softmax over T per batch; sums the 4 score slices; writes weights.
// ---------------------------------------------------------------------------
__global__ void softmax_kernel(const float* __restrict__ sP,
                               float* __restrict__ out) {
    const int b = blockIdx.x;
    const int tid = threadIdx.x;

    float v[8];
    float mx = -1e30f;
#pragma unroll
    for (int i = 0; i < 8; ++i) {
        int m = b * T_DIM + i * 256 + tid;
        v[i] = sP[m] + sP[M_DIM + m] + sP[2 * M_DIM + m] + sP[3 * M_DIM + m];
        mx = fmaxf(mx, v[i]);
    }
#pragma unroll
    for (int off = 1; off < 64; off <<= 1)
        mx = fmaxf(mx, __shfl_xor(mx, off, 64));
    __shared__ float redm[4];
    if ((tid & 63) == 0) redm[tid >> 6] = mx;
    __syncthreads();
    mx = fmaxf(fmaxf(redm[0], redm[1]), fmaxf(redm[2], redm[3]));

    float sum = 0.f;
#pragma unroll
    for (int i = 0; i < 8; ++i) {
        v[i] = __expf(v[i] - mx);
        sum += v[i];
    }
#pragma unroll
    for (int off = 1; off < 64; off <<= 1)
        sum += __shfl_xor(sum, off, 64);
    __shared__ float reds[4];
    if ((tid & 63) == 0) reds[tid >> 6] = sum;
    __syncthreads();
    sum = reds[0] + reds[1] + reds[2] + reds[3];

    const float inv = 1.0f / sum;
#pragma unroll
    for (int i = 0; i < 8; ++i)
        out[B_DIM * D_DIM + b * T_DIM + i * 256 + tid] = v[i] * inv;
}

// ---------------------------------------------------------------------------
// Kernel 4: context partials. grid (32 tc, 32 b) x 256 thr. Block = 64 t x
// 512 d; two t-interleaved halves combined in LDS; partial -> P (no atomics).
// ---------------------------------------------------------------------------
__global__ void context_kernel(const float* __restrict__ values,
                               const float* __restrict__ weights,
                               float* __restrict__ P) {
    __shared__ float sw[64];
    __shared__ float red[512];
    const int tc = blockIdx.x;   // 0..31 (64 t each)
    const int b  = blockIdx.y;
    const int tid = threadIdx.x;
    const int d4 = tid & 127;    // float4 column
    const int th = tid >> 7;     // t-interleave half

    if (tid < 64) sw[tid] = weights[b * T_DIM + tc * 64 + tid];
    __syncthreads();

    const float4* vb = (const float4*)(values + ((size_t)b * T_DIM + tc * 64) * D_DIM) + d4;
    float4 acc = {0.f, 0.f, 0.f, 0.f};
#pragma unroll 8
    for (int i = th; i < 64; i += 2) {
        float wv = sw[i];
        float4 vv = vb[(size_t)i * 128];
        acc.x += wv * vv.x; acc.y += wv * vv.y;
        acc.z += wv * vv.z; acc.w += wv * vv.w;
    }
    if (th == 1) ((float4*)red)[d4] = acc;
    __syncthreads();
    if (th == 0) {
        float4 o = ((float4*)red)[d4];
        acc.x += o.x; acc.y += o.y; acc.z += o.z; acc.w += o.w;
        *(float4*)(P + ((size_t)(b * 32 + tc)) * 512 + d4 * 4) = acc;
    }
}

// Kernel 5: reduce the 32 t-chunk partials -> context output.
__global__ void reduce_kernel(const float* __restrict__ P,
                              float* __restrict__ ctx) {
    const int g = blockIdx.x * 256 + threadIdx.x;   // 0..16383
    const int b = g >> 9, d = g & 511;
    float s = 0.f;
#pragma unroll
    for (int tc = 0; tc < 32; ++tc)
        s += P[((size_t)(b * 32 + tc)) * 512 + d];
    ctx[g] = s;
}

// ---------------------------------------------------------------------------
extern "C" void kernel_launch(void* const* d_in, const int* in_sizes, int n_in,
                              void* d_out, int out_size, void* d_ws, size_t ws_size,
                              hipStream_t stream) {
    const float* values = (const float*)d_in[0];
    const float* query  = (const float*)d_in[1];
    const float* W1_w   = (const float*)d_in[2];
    const float* W1_b   = (const float*)d_in[3];
    const float* W2_w   = (const float*)d_in[4];
    const float* W2_b   = (const float*)d_in[5];
    const float* V_w    = (const float*)d_in[6];
    // V_b (d_in[7]) dropped: softmax is shift-invariant.

    float* out = (float*)d_out;

    unsigned char* ws = (unsigned char*)d_ws;
    unsigned short* W1T = (unsigned short*)(ws);             // 512 KiB
    float* qb = (float*)(ws + 524288);                       // 64 KiB
    float* sP = (float*)(ws + 524288 + 65536);               // 1 MiB (4 slices)
    float* P  = (float*)(ws + 524288 + 65536 + 1048576);     // 2 MiB

    prep_kernel<<<384, 256, 0, stream>>>(W1_w, W1_b, W2_w, W2_b, query, W1T, qb);
    score_kernel<<<1024, 512, 0, stream>>>(values, W1T, qb, V_w, sP);
    softmax_kernel<<<B_DIM, 256, 0, stream>>>(sP, out);
    context_kernel<<<dim3(32, B_DIM), 256, 0, stream>>>(values, out + B_DIM * D_DIM, P);
    reduce_kernel<<<64, 256, 0, stream>>>(P, out);
}